// Round 4
// baseline (285.531 us; speedup 1.0000x reference)
//
#include <hip/hip_runtime.h>

// Gaussian blur 21x21, sigma=5, depthwise over [B=32, C=3, H=512, W=512] fp32,
// reflect padding, separable, fused single kernel.
//
// R4: single-LDS-buffer restructure.
//  - Stage A (horizontal): read directly from GLOBAL (L1/L2 absorb halo
//    re-reads), 8 outputs/thread via 8 float4 loads, write h -> s_h.
//    s_h row stride 68: b128 write quad-offsets (4r+8c)%32 hit all 8 quad
//    groups exactly 8x per wave -> balanced (stride 64 is 2x imbalanced).
//  - Stage B (vertical): wave = 16-row x 64-col strip, lane=x, b32 reads at
//    wave-uniform row + lane offset -> 2 lanes/bank -> conflict-free.
//  - Weights are compile-time literals (VOP2 fmac literal) -> ~21 fewer VGPRs.
//  - LDS 22.3 KB (was 50 KB) -> 7 blocks/CU; one barrier (was two).

#define KS   21
#define PAD  10
#define TILE 64
#define LH   (TILE + 2 * PAD)   // 84 h-rows per block
#define SW_H 68                 // s_h row stride (pad +4)
#define IMG  512
#define NTHREADS 256

// exp(-(k-10)^2/50), normalized; sum(outer(g,g))=sum(g)^2 so 1-D normalization
// reproduces the reference's 2-D normalization. Literal error ~1e-6 << 7e-3.
#define GW(i) W[i]
__device__ __constant__ float c_unused; // (keep object layout trivial)

__global__ __launch_bounds__(NTHREADS) void gauss_blur_kernel(
    const float* __restrict__ in, float* __restrict__ out)
{
    __shared__ __align__(16) float s_h[LH * SW_H];   // 84*68*4 = 22848 B

    constexpr float W[KS] = {
        0.011194717f, 0.016369860f, 0.022998804f, 0.031045124f, 0.040263373f,
        0.050171245f, 0.060066033f, 0.069092259f, 0.076358728f, 0.081080459f,
        0.082718387f,
        0.081080459f, 0.076358728f, 0.069092259f, 0.060066033f, 0.050171245f,
        0.040263373f, 0.031045124f, 0.022998804f, 0.016369860f, 0.011194717f
    };

    const int tid   = threadIdx.x;
    const int plane = blockIdx.z;                 // b*C + c, 0..95
    const int x0    = blockIdx.x * TILE;
    const int y0    = blockIdx.y * TILE;

    const float* __restrict__ pin = in + (size_t)plane * (IMG * IMG);

    const bool x_interior = (blockIdx.x != 0) && (blockIdx.x != (IMG / TILE - 1));

    // ---- stage A: horizontal 21-tap from GLOBAL -> s_h (84 rows x 64 cols) ----
    // item: (row ly 0..83, col-group lx 0,8,...,56); 672 items, 8 outputs each.
    // output col lx+j needs gx = x0+lx+j-10+k; window v[t]=pin[.. x0-12+lx+t],
    // t=0..31 (aligned: (x0-12)*4 % 16 == 0), out_j = sum_k W[k]*v[2+j+k].
    if (x_interior) {
#pragma unroll
        for (int it = 0; it < 3; ++it) {
            int idx = tid + it * NTHREADS;
            if (idx < LH * (TILE / 8)) {
                int ly = idx >> 3;
                int lx = (idx & 7) << 3;
                int gy = y0 + ly - PAD;
                gy = (gy < 0) ? -gy : ((gy >= IMG) ? (2 * IMG - 2 - gy) : gy);
                const float4* __restrict__ rp =
                    (const float4*)&pin[(size_t)gy * IMG + (x0 - 12) + lx];
                float v[32];
#pragma unroll
                for (int t = 0; t < 8; ++t) {
                    float4 f = rp[t];
                    v[4 * t + 0] = f.x; v[4 * t + 1] = f.y;
                    v[4 * t + 2] = f.z; v[4 * t + 3] = f.w;
                }
                float a[8] = {0, 0, 0, 0, 0, 0, 0, 0};
#pragma unroll
                for (int k = 0; k < KS; ++k) {
#pragma unroll
                    for (int j = 0; j < 8; ++j) a[j] += W[k] * v[2 + j + k];
                }
                *(float4*)&s_h[ly * SW_H + lx]     = make_float4(a[0], a[1], a[2], a[3]);
                *(float4*)&s_h[ly * SW_H + lx + 4] = make_float4(a[4], a[5], a[6], a[7]);
            }
        }
    } else {
        // x-border blocks: scalar window build with x-reflect (28 loads / 8 outs)
#pragma unroll
        for (int it = 0; it < 3; ++it) {
            int idx = tid + it * NTHREADS;
            if (idx < LH * (TILE / 8)) {
                int ly = idx >> 3;
                int lx = (idx & 7) << 3;
                int gy = y0 + ly - PAD;
                gy = (gy < 0) ? -gy : ((gy >= IMG) ? (2 * IMG - 2 - gy) : gy);
                const float* __restrict__ row = &pin[(size_t)gy * IMG];
                float v[28];
#pragma unroll
                for (int t = 0; t < 28; ++t) {
                    int gx = x0 + lx - 10 + t;
                    gx = (gx < 0) ? -gx : ((gx >= IMG) ? (2 * IMG - 2 - gx) : gx);
                    v[t] = row[gx];
                }
                float a[8] = {0, 0, 0, 0, 0, 0, 0, 0};
#pragma unroll
                for (int k = 0; k < KS; ++k) {
#pragma unroll
                    for (int j = 0; j < 8; ++j) a[j] += W[k] * v[j + k];
                }
                *(float4*)&s_h[ly * SW_H + lx]     = make_float4(a[0], a[1], a[2], a[3]);
                *(float4*)&s_h[ly * SW_H + lx + 4] = make_float4(a[4], a[5], a[6], a[7]);
            }
        }
    }
    __syncthreads();

    // ---- stage B: vertical 21-tap, wave = 16-row x 64-col strip, lane = x ----
    {
        const int wv = tid >> 6;          // wave 0..3
        const int x  = tid & 63;
        const int oy = wv << 4;           // 0,16,32,48

        float acc[16];
#pragma unroll
        for (int j = 0; j < 16; ++j) acc[j] = 0.f;

#pragma unroll
        for (int t = 0; t < 36; ++t) {    // s_h rows oy..oy+35 (16 outs + 20 halo)
            float r = s_h[(oy + t) * SW_H + x];
#pragma unroll
            for (int j = 0; j < 16; ++j)
                if (j >= t - (KS - 1) && j <= t) acc[j] += W[t - j] * r;
        }

        float* __restrict__ pout = out + (size_t)plane * (IMG * IMG)
                                       + (size_t)(y0 + oy) * IMG + x0 + x;
#pragma unroll
        for (int j = 0; j < 16; ++j) pout[(size_t)j * IMG] = acc[j];
    }
}

extern "C" void kernel_launch(void* const* d_in, const int* in_sizes, int n_in,
                              void* d_out, int out_size, void* d_ws, size_t ws_size,
                              hipStream_t stream)
{
    const float* x = (const float*)d_in[0];
    float* out = (float*)d_out;

    dim3 grid(IMG / TILE, IMG / TILE, 96);   // 8 x 8 x (32*3) planes
    dim3 block(NTHREADS);
    gauss_blur_kernel<<<grid, block, 0, stream>>>(x, out);
}